// Round 1
// baseline (4905.022 us; speedup 1.0000x reference)
//
#include <hip/hip_runtime.h>
#include <hip/hip_bf16.h>
#include <math.h>

#define B 2
#define S 2048
#define EMB 2048
#define NH 16
#define NKV 4
#define HD 128
#define EPS 1e-6f

// ---------------- GEMM: C = A(MxK) @ W(KxN), fp32 ----------------
// HEADS==0: plain row-major C[m][n].
// HEADS>0 : scatter to (b, h, s, d) layout: C[((b*HEADS+h)*S+s)*HD+d],
//           with b=m/S, s=m%S, h=n/HD, d=n%HD.
template<int HEADS>
__global__ __launch_bounds__(256) void gemm_f32(const float* __restrict__ A,
                                                const float* __restrict__ W,
                                                float* __restrict__ C,
                                                int M, int N, int K)
{
    __shared__ float As[64][17];   // 64 rows x 16 k (+1 pad)
    __shared__ float Ws[16][64];   // 16 k x 64 cols
    const int tid = threadIdx.x;
    const int ty = tid >> 4, tx = tid & 15;
    const int m0 = blockIdx.y * 64, n0 = blockIdx.x * 64;

    float acc[4][4];
#pragma unroll
    for (int i = 0; i < 4; ++i)
#pragma unroll
        for (int j = 0; j < 4; ++j) acc[i][j] = 0.f;

    for (int k0 = 0; k0 < K; k0 += 16) {
#pragma unroll
        for (int i = 0; i < 4; ++i) {
            int idx = tid + i * 256;           // 1024 elements
            int r = idx >> 4, c = idx & 15;
            As[r][c] = A[(size_t)(m0 + r) * K + k0 + c];
        }
#pragma unroll
        for (int i = 0; i < 4; ++i) {
            int idx = tid + i * 256;
            int r = idx >> 6, c = idx & 63;
            Ws[r][c] = W[(size_t)(k0 + r) * N + n0 + c];
        }
        __syncthreads();
#pragma unroll
        for (int kk = 0; kk < 16; ++kk) {
            float a[4], b[4];
#pragma unroll
            for (int i = 0; i < 4; ++i) a[i] = As[ty * 4 + i][kk];
#pragma unroll
            for (int j = 0; j < 4; ++j) b[j] = Ws[kk][tx * 4 + j];
#pragma unroll
            for (int i = 0; i < 4; ++i)
#pragma unroll
                for (int j = 0; j < 4; ++j) acc[i][j] += a[i] * b[j];
        }
        __syncthreads();
    }

#pragma unroll
    for (int i = 0; i < 4; ++i) {
        int m = m0 + ty * 4 + i;
#pragma unroll
        for (int j = 0; j < 4; ++j) {
            int n = n0 + tx * 4 + j;
            if (HEADS == 0) {
                C[(size_t)m * N + n] = acc[i][j];
            } else {
                int bb = m / S, ss = m % S;
                int h = n / HD, d = n & (HD - 1);
                C[(((size_t)bb * HEADS + h) * S + ss) * HD + d] = acc[i][j];
            }
        }
    }
}

// ------------- fused RMSNorm (+optional weight) + optional RoPE -------------
// One 128-thread block per row of HD elements; in-place.
__global__ __launch_bounds__(128) void norm_rope(float* __restrict__ buf,
                                                 const float* __restrict__ w,
                                                 const float* __restrict__ cosb,
                                                 const float* __restrict__ sinb,
                                                 int do_rope)
{
    const int row = blockIdx.x;           // (b*heads + h)*S + s
    const int s = row & (S - 1);
    const int d = threadIdx.x;
    float* p = buf + (size_t)row * HD;

    float xv = p[d];
    float ss = xv * xv;
#pragma unroll
    for (int off = 32; off > 0; off >>= 1) ss += __shfl_down(ss, off);

    __shared__ float wsum[2];
    __shared__ float xs[HD];
    const int lane = d & 63, wid = d >> 6;
    if (lane == 0) wsum[wid] = ss;
    __syncthreads();
    float ms = (wsum[0] + wsum[1]) * (1.f / HD) + EPS;
    float xn = xv * rsqrtf(ms);
    if (w) xn *= w[d];
    if (do_rope) {
        xs[d] = xn;
        __syncthreads();
        float rot = (d < 64) ? -xs[d + 64] : xs[d - 64];
        xn = xn * cosb[(size_t)s * HD + d] + rot * sinb[(size_t)s * HD + d];
    }
    p[d] = xn;
}

// ---------------- causal GQA flash attention, fp32 ----------------
// grid: (S/64, NH, B); 256 threads. Q tile 64x128; K/V tiles share LDS.
__global__ __launch_bounds__(256) void attn(const float* __restrict__ q,
                                            const float* __restrict__ k,
                                            const float* __restrict__ v,
                                            float* __restrict__ ctx)
{
    const int qt = blockIdx.x, h = blockIdx.y, b = blockIdx.z;
    const int kv = h / (NH / NKV);
    const int q0 = qt * 64;

    __shared__ float Qs[64][HD];
    __shared__ float KVs[64][HD];
    __shared__ float Ps[64][65];
    __shared__ float mrow[64], lrow[64], arow[64];

    const int tid = threadIdx.x;
    const int ty = tid >> 4, tx = tid & 15;

    const float* qbase = q + (((size_t)b * NH + h) * S + q0) * HD;
    const float* kbase = k + (((size_t)b * NKV + kv) * S) * HD;
    const float* vbase = v + (((size_t)b * NKV + kv) * S) * HD;

    for (int i = tid; i < 64 * HD; i += 256) Qs[i >> 7][i & 127] = qbase[i];
    if (tid < 64) { mrow[tid] = -INFINITY; lrow[tid] = 0.f; }

    float acc[4][8];
#pragma unroll
    for (int i = 0; i < 4; ++i)
#pragma unroll
        for (int j = 0; j < 8; ++j) acc[i][j] = 0.f;
    __syncthreads();

    for (int kt = 0; kt <= qt; ++kt) {
        for (int i = tid; i < 64 * HD; i += 256)
            KVs[i >> 7][i & 127] = kbase[(size_t)kt * 64 * HD + i];
        __syncthreads();

        // scores: 4 rows x 4 cols per thread
        float sc[4][4];
#pragma unroll
        for (int i = 0; i < 4; ++i)
#pragma unroll
            for (int j = 0; j < 4; ++j) sc[i][j] = 0.f;

        for (int d = 0; d < HD; ++d) {
            float qr[4], kc[4];
#pragma unroll
            for (int i = 0; i < 4; ++i) qr[i] = Qs[ty * 4 + i][d];
#pragma unroll
            for (int j = 0; j < 4; ++j) kc[j] = KVs[tx * 4 + j][d];
#pragma unroll
            for (int i = 0; i < 4; ++i)
#pragma unroll
                for (int j = 0; j < 4; ++j) sc[i][j] += qr[i] * kc[j];
        }
#pragma unroll
        for (int i = 0; i < 4; ++i)
#pragma unroll
            for (int j = 0; j < 4; ++j) {
                int r = ty * 4 + i, c = tx * 4 + j;
                float sv = sc[i][j];
                if (kt * 64 + c > q0 + r) sv = -INFINITY;   // causal mask
                Ps[r][c] = sv;
            }
        __syncthreads();

        // online softmax, one thread per row (baseline; parallelize later)
        if (tid < 64) {
            float mold = mrow[tid];
            float mx = mold;
#pragma unroll 8
            for (int c = 0; c < 64; ++c) mx = fmaxf(mx, Ps[tid][c]);
            float alpha = (mold == -INFINITY) ? 0.f : __expf(mold - mx);
            float l = lrow[tid] * alpha;
            for (int c = 0; c < 64; ++c) {
                float pp = __expf(Ps[tid][c] - mx);
                Ps[tid][c] = pp;
                l += pp;
            }
            mrow[tid] = mx; lrow[tid] = l; arow[tid] = alpha;
        }
        __syncthreads();

        // load V over KVs (all K reads completed before scores barrier)
        for (int i = tid; i < 64 * HD; i += 256)
            KVs[i >> 7][i & 127] = vbase[(size_t)kt * 64 * HD + i];
        __syncthreads();

        // rescale + PV: 4 rows x 8 dims per thread
#pragma unroll
        for (int i = 0; i < 4; ++i) {
            float al = arow[ty * 4 + i];
#pragma unroll
            for (int j = 0; j < 8; ++j) acc[i][j] *= al;
        }
        for (int jj = 0; jj < 64; ++jj) {
            float pr[4], vv[8];
#pragma unroll
            for (int i = 0; i < 4; ++i) pr[i] = Ps[ty * 4 + i][jj];
#pragma unroll
            for (int j = 0; j < 8; ++j) vv[j] = KVs[jj][tx * 8 + j];
#pragma unroll
            for (int i = 0; i < 4; ++i)
#pragma unroll
                for (int j = 0; j < 8; ++j) acc[i][j] += pr[i] * vv[j];
        }
        __syncthreads();   // protect KVs/Ps before next iteration
    }

    // epilogue: write ctx in (b, s, h*HD+d) layout
#pragma unroll
    for (int i = 0; i < 4; ++i) {
        int r = ty * 4 + i;
        float inv = 1.f / lrow[r];
#pragma unroll
        for (int j = 0; j < 8; ++j) {
            int d = tx * 8 + j;
            ctx[((size_t)b * S + q0 + r) * EMB + (size_t)h * HD + d] = acc[i][j] * inv;
        }
    }
}

extern "C" void kernel_launch(void* const* d_in, const int* in_sizes, int n_in,
                              void* d_out, int out_size, void* d_ws, size_t ws_size,
                              hipStream_t stream) {
    const float* x    = (const float*)d_in[0];
    // d_in[1] = mask (bool) — causal triu, implemented directly, ignored here
    const float* cosb = (const float*)d_in[2];
    const float* sinb = (const float*)d_in[3];
    const float* Wq   = (const float*)d_in[4];
    const float* Wk   = (const float*)d_in[5];
    const float* Wv   = (const float*)d_in[6];
    const float* Wo   = (const float*)d_in[7];
    const float* qw   = (const float*)d_in[8];
    const float* kw   = (const float*)d_in[9];
    float* out = (float*)d_out;

    float* ws   = (float*)d_ws;
    float* qbuf = ws;                                  // B*NH*S*HD  = 8.39M f32
    float* kbuf = qbuf + (size_t)B * NH * S * HD;      // B*NKV*S*HD = 2.10M
    float* vbuf = kbuf + (size_t)B * NKV * S * HD;     // 2.10M
    float* ctx  = vbuf + (size_t)B * NKV * S * HD;     // 8.39M  (total 80 MB)

    const int M = B * S;           // 4096
    dim3 blk(256);

    gemm_f32<NH> <<<dim3((NH * HD) / 64, M / 64), blk, 0, stream>>>(x, Wq, qbuf, M, NH * HD, EMB);
    gemm_f32<NKV><<<dim3((NKV * HD) / 64, M / 64), blk, 0, stream>>>(x, Wk, kbuf, M, NKV * HD, EMB);
    gemm_f32<NKV><<<dim3((NKV * HD) / 64, M / 64), blk, 0, stream>>>(x, Wv, vbuf, M, NKV * HD, EMB);

    norm_rope<<<B * NH * S, 128, 0, stream>>>(qbuf, qw, cosb, sinb, 1);
    norm_rope<<<B * NKV * S, 128, 0, stream>>>(kbuf, kw, cosb, sinb, 1);
    norm_rope<<<B * NKV * S, 128, 0, stream>>>(vbuf, nullptr, nullptr, nullptr, 0);

    attn<<<dim3(S / 64, NH, B), blk, 0, stream>>>(qbuf, kbuf, vbuf, ctx);

    gemm_f32<0><<<dim3(EMB / 64, M / 64), blk, 0, stream>>>(ctx, Wo, out, M, EMB, EMB);
}

// Round 5
// 776.391 us; speedup vs baseline: 6.3177x; 6.3177x over previous
//
#include <hip/hip_runtime.h>
#include <hip/hip_bf16.h>
#include <math.h>
#include <stdint.h>

#define B 2
#define S 2048
#define EMB 2048
#define NH 16
#define NKV 4
#define HD 128
#define EPS 1e-6f

typedef __attribute__((ext_vector_type(8))) short short8v;   // 8 bf16 = 4 VGPR
typedef __attribute__((ext_vector_type(4))) float float4v;

static __device__ inline unsigned short f2bf(float x) {
    __hip_bfloat16 h = __float2bfloat16(x);
    return *(unsigned short*)&h;
}
static __device__ inline float bf2f(short s) {
    __hip_bfloat16 h = *(__hip_bfloat16*)&s;
    return __bfloat162float(h);
}

// async global(16B/lane) -> LDS (linear: wave-uniform base + lane*16)
static __device__ inline void gload_lds16(const void* g, void* l) {
    __builtin_amdgcn_global_load_lds(
        reinterpret_cast<const __attribute__((address_space(1))) unsigned int*>(
            reinterpret_cast<uintptr_t>(g)),
        reinterpret_cast<__attribute__((address_space(3))) unsigned int*>(
            reinterpret_cast<uintptr_t>(l)),
        16, 0, 0);
}

// ------------- transpose W[K][N] f32 -> Wt[N][K] bf16 (single) -------------
__global__ __launch_bounds__(256) void transpose_cast(const float* __restrict__ W,
                                                      short* __restrict__ Wt,
                                                      int K, int N)
{
    __shared__ float tile[32][33];
    const int n0 = blockIdx.x * 32, k0 = blockIdx.y * 32;
    const int tx = threadIdx.x & 31, ty = threadIdx.x >> 5;
#pragma unroll
    for (int i = 0; i < 4; ++i)
        tile[ty + i * 8][tx] = W[(size_t)(k0 + ty + i * 8) * N + n0 + tx];
    __syncthreads();
#pragma unroll
    for (int i = 0; i < 4; ++i) {
        int nr = ty + i * 8;
        Wt[(size_t)(n0 + nr) * K + k0 + tx] = (short)f2bf(tile[tx][nr]);
    }
}

// ------- transpose W[K][N] f32 -> hi/lo bf16 pair Wt_h/Wt_l [N][K] -------
__global__ __launch_bounds__(256) void transpose_split(const float* __restrict__ W,
                                                       short* __restrict__ Wth,
                                                       short* __restrict__ Wtl,
                                                       int K, int N)
{
    __shared__ float tile[32][33];
    const int n0 = blockIdx.x * 32, k0 = blockIdx.y * 32;
    const int tx = threadIdx.x & 31, ty = threadIdx.x >> 5;
#pragma unroll
    for (int i = 0; i < 4; ++i)
        tile[ty + i * 8][tx] = W[(size_t)(k0 + ty + i * 8) * N + n0 + tx];
    __syncthreads();
#pragma unroll
    for (int i = 0; i < 4; ++i) {
        int nr = ty + i * 8;
        float wv = tile[tx][nr];
        short hi = (short)f2bf(wv);
        short lo = (short)f2bf(wv - bf2f(hi));
        Wth[(size_t)(n0 + nr) * K + k0 + tx] = hi;
        Wtl[(size_t)(n0 + nr) * K + k0 + tx] = lo;
    }
}

// ------- QKV GEMM: C = A(f32, MxK) @ (Bh+Bl)(bf16, NxK)^T, fp32 out -------
// 128x128 tile, BK=64, 4 waves. A reg-staged f32->bf16 (single round),
// XOR-swizzled; Bh/Bl via global_load_lds. 2 MFMA passes (split-W).
template<int HEADS>
__global__ __launch_bounds__(256) void gemm_split(const float* __restrict__ A,
                                                  const short* __restrict__ Bh,
                                                  const short* __restrict__ Bl,
                                                  float* __restrict__ C,
                                                  int M, int N, int K)
{
    __shared__ __align__(16) short Ash[128 * 64];   // 16 KB, swizzled
    __shared__ __align__(16) short Bsh[128 * 64];   // 16 KB, linear
    __shared__ __align__(16) short Bsl[128 * 64];   // 16 KB, linear
    const int tid = threadIdx.x;
    const int w = tid >> 6, l = tid & 63;
    const int wr = w >> 1, wc = w & 1;
    const int lc = l & 15, lg = l >> 4;
    const int m0 = blockIdx.y * 128, n0 = blockIdx.x * 128;

    float4v acc[4][4];
#pragma unroll
    for (int mi = 0; mi < 4; ++mi)
#pragma unroll
        for (int ni = 0; ni < 4; ++ni) acc[mi][ni] = (float4v){0.f, 0.f, 0.f, 0.f};

    // B staging geometry (linear, 16B/lane)
    const int srow = tid >> 3;
    const int scol = (tid & 7) * 8;
    const short* bhg = Bh + (size_t)(n0 + srow) * K + scol;
    const short* blg = Bl + (size_t)(n0 + srow) * K + scol;
    char* bshl = (char*)Bsh + tid * 16;
    char* bsll = (char*)Bsl + tid * 16;

    // A staging geometry (reg-staged): thread t -> row t>>1, half t&1 (32 f32)
    const int arow = tid >> 1, ahalf = tid & 1;
    const float* ag = A + (size_t)(m0 + arow) * K + ahalf * 32;

    for (int k0 = 0; k0 < K; k0 += 64) {
#pragma unroll
        for (int is = 0; is < 4; ++is) {
            gload_lds16(bhg + (size_t)is * 32 * K + k0, bshl + is * 4096);
            gload_lds16(blg + (size_t)is * 32 * K + k0, bsll + is * 4096);
        }
        // A: 32 f32 -> 32 bf16, 4 swizzled 16B chunks (chunk = (4h+c)^(row&7))
        {
            const float* ap = ag + k0;
            float4v f[8];
#pragma unroll
            for (int i = 0; i < 8; ++i) f[i] = *(const float4v*)(ap + i * 4);
#pragma unroll
            for (int c = 0; c < 4; ++c) {
                short8v hv;
#pragma unroll
                for (int j = 0; j < 8; ++j) hv[j] = (short)f2bf(f[2 * c + (j >> 2)][j & 3]);
                int chunk = (4 * ahalf + c) ^ (arow & 7);
                *(short8v*)(&Ash[arow * 64 + chunk * 8]) = hv;
            }
        }
        __syncthreads();

#pragma unroll
        for (int kk = 0; kk < 2; ++kk) {
            short8v af[4], bh[4], bl[4];
#pragma unroll
            for (int mi = 0; mi < 4; ++mi) {
                int row = wr * 64 + mi * 16 + lc;
                int chunk = (kk * 4 + lg) ^ (row & 7);
                af[mi] = *(const short8v*)(&Ash[row * 64 + chunk * 8]);
            }
#pragma unroll
            for (int ni = 0; ni < 4; ++ni) {
                int row = wc * 64 + ni * 16 + lc;
                bh[ni] = *(const short8v*)(Bsh + row * 64 + kk * 32 + lg * 8);
                bl[ni] = *(const short8v*)(Bsl + row * 64 + kk * 32 + lg * 8);
            }
#pragma unroll
            for (int mi = 0; mi < 4; ++mi)
#pragma unroll
                for (int ni = 0; ni < 4; ++ni) {
                    acc[mi][ni] = __builtin_amdgcn_mfma_f32_16x16x32_bf16(af[mi], bh[ni], acc[mi][ni], 0, 0, 0);
                    acc[mi][ni] = __builtin_amdgcn_mfma_f32_16x16x32_bf16(af[mi], bl[ni], acc[mi][ni], 0, 0, 0);
                }
        }
        __syncthreads();
    }

    // epilogue: D col=lane&15, row=(lane>>4)*4+r
#pragma unroll
    for (int mi = 0; mi < 4; ++mi)
#pragma unroll
        for (int ni = 0; ni < 4; ++ni)
#pragma unroll
            for (int r = 0; r < 4; ++r) {
                int m = m0 + wr * 64 + mi * 16 + lg * 4 + r;
                int n = n0 + wc * 64 + ni * 16 + lc;
                float val = acc[mi][ni][r];
                if (HEADS == 0) {
                    C[(size_t)m * N + n] = val;
                } else {
                    int bb = m >> 11, ss = m & (S - 1);
                    int hh = n >> 7,  dd = n & (HD - 1);
                    C[(((size_t)bb * HEADS + hh) * S + ss) * HD + dd] = val;
                }
            }
}

// ------- Wo GEMM: C = A(bf16, MxK) @ Bt(bf16, NxK)^T, fp32 out (m97-ish) -----
__global__ __launch_bounds__(256) void gemm_bf16(const short* __restrict__ A,
                                                 const short* __restrict__ Bt,
                                                 float* __restrict__ C,
                                                 int M, int N, int K)
{
    __shared__ __align__(16) short As[128 * 64];
    __shared__ __align__(16) short Bs[128 * 64];
    const int tid = threadIdx.x;
    const int w = tid >> 6, l = tid & 63;
    const int wr = w >> 1, wc = w & 1;
    const int lc = l & 15, lg = l >> 4;
    const int m0 = blockIdx.y * 128, n0 = blockIdx.x * 128;

    float4v acc[4][4];
#pragma unroll
    for (int mi = 0; mi < 4; ++mi)
#pragma unroll
        for (int ni = 0; ni < 4; ++ni) acc[mi][ni] = (float4v){0.f, 0.f, 0.f, 0.f};

    const int srow = tid >> 3;
    const int scol = (tid & 7) * 8;
    const short* ag = A  + (size_t)(m0 + srow) * K + scol;
    const short* bg = Bt + (size_t)(n0 + srow) * K + scol;
    char* asl = (char*)As + tid * 16;
    char* bsl = (char*)Bs + tid * 16;

    for (int k0 = 0; k0 < K; k0 += 64) {
#pragma unroll
        for (int is = 0; is < 4; ++is) {
            gload_lds16(ag + (size_t)is * 32 * K + k0, asl + is * 4096);
            gload_lds16(bg + (size_t)is * 32 * K + k0, bsl + is * 4096);
        }
        __syncthreads();
#pragma unroll
        for (int kk = 0; kk < 2; ++kk) {
            short8v af[4], bf[4];
#pragma unroll
            for (int mi = 0; mi < 4; ++mi)
                af[mi] = *(const short8v*)(As + (wr * 64 + mi * 16 + lc) * 64 + kk * 32 + lg * 8);
#pragma unroll
            for (int ni = 0; ni < 4; ++ni)
                bf[ni] = *(const short8v*)(Bs + (wc * 64 + ni * 16 + lc) * 64 + kk * 32 + lg * 8);
#pragma unroll
            for (int mi = 0; mi < 4; ++mi)
#pragma unroll
                for (int ni = 0; ni < 4; ++ni)
                    acc[mi][ni] = __builtin_amdgcn_mfma_f32_16x16x32_bf16(af[mi], bf[ni], acc[mi][ni], 0, 0, 0);
        }
        __syncthreads();
    }

#pragma unroll
    for (int mi = 0; mi < 4; ++mi)
#pragma unroll
        for (int ni = 0; ni < 4; ++ni)
#pragma unroll
            for (int r = 0; r < 4; ++r) {
                int m = m0 + wr * 64 + mi * 16 + lg * 4 + r;
                int n = n0 + wc * 64 + ni * 16 + lc;
                C[(size_t)m * N + n] = acc[mi][ni][r];
            }
}

// ------- fused RMSNorm (+weight) + optional RoPE, fp32 in-place -------
__global__ __launch_bounds__(128) void norm_rope(float* __restrict__ buf,
                                                 const float* __restrict__ w,
                                                 const float* __restrict__ cosb,
                                                 const float* __restrict__ sinb,
                                                 int do_rope)
{
    const int row = blockIdx.x;
    const int s = row & (S - 1);
    const int d = threadIdx.x;
    float* p = buf + (size_t)row * HD;

    float xv = p[d];
    float ss = xv * xv;
#pragma unroll
    for (int off = 32; off > 0; off >>= 1) ss += __shfl_down(ss, off);

    __shared__ float wsum[2];
    __shared__ float xs[HD];
    const int lane = d & 63, wid = d >> 6;
    if (lane == 0) wsum[wid] = ss;
    __syncthreads();
    float ms = (wsum[0] + wsum[1]) * (1.f / HD) + EPS;
    float xn = xv * rsqrtf(ms);
    if (w) xn *= w[d];
    if (do_rope) {
        xs[d] = xn;
        __syncthreads();
        float rot = (d < 64) ? -xs[d + 64] : xs[d - 64];
        xn = xn * cosb[(size_t)s * HD + d] + rot * sinb[(size_t)s * HD + d];
    }
    p[d] = xn;
}

// ---------------- causal GQA flash attention, split-precision MFMA -----------
// grid (S/64, NH, B), 4 waves. q,k,v fp32. QK^T 3-pass (Kh·Qh+Kl·Qh+Kh·Ql) so
// score error ~ upstream only. Swapped QK^T: softmax reduce = 2x shfl_xor.
__global__ __launch_bounds__(256) void attn_mfma(const float* __restrict__ q,
                                                 const float* __restrict__ k,
                                                 const float* __restrict__ v,
                                                 short* __restrict__ ctx)   // bf16 out
{
    const int qt = blockIdx.x, h = blockIdx.y, b = blockIdx.z;
    const int kvh = h >> 2;
    const int q0 = qt * 64;
    const int tid = threadIdx.x;
    const int w  = tid >> 6;
    const int l  = tid & 63;
    const int lg = l >> 4;
    const int lc = l & 15;

    __shared__ __align__(16) short Ksh[64 * 128];   // 16 KB, swizzled hi
    __shared__ __align__(16) short Ksl[64 * 128];   // 16 KB, swizzled lo
    __shared__ __align__(16) short Vt[128][72];     // 18 KB, transposed+pad
    __shared__ __align__(16) short Pl[4][16][72];   // 9 KB per-wave P

    const float* qbase = q + (((size_t)b * NH + h) * S + q0 + w * 16) * HD;
    const float* kbase = k + (((size_t)b * NKV + kvh) * S) * HD;
    const float* vbase = v + (((size_t)b * NKV + kvh) * S) * HD;

    // Q fragments hi/lo (exact split of fp32)
    short8v qh[4], ql[4];
#pragma unroll
    for (int ks = 0; ks < 4; ++ks) {
        const float* qp = qbase + lc * HD + ks * 32 + lg * 8;
        float4v a = *(const float4v*)qp;
        float4v bq = *(const float4v*)(qp + 4);
#pragma unroll
        for (int j = 0; j < 8; ++j) {
            float fv = (j < 4) ? a[j] : bq[j - 4];
            short hi = (short)f2bf(fv);
            qh[ks][j] = hi;
            ql[ks][j] = (short)f2bf(fv - bf2f(hi));
        }
    }

    float4v o[8];
#pragma unroll
    for (int nf = 0; nf < 8; ++nf) o[nf] = (float4v){0.f, 0.f, 0.f, 0.f};
    float m_run = -INFINITY, l_run = 0.f;
    const int q_abs = q0 + w * 16 + lc;

    for (int kt = 0; kt <= qt; ++kt) {
        // ---- stage K (f32 -> hi/lo bf16, swizzled): thread: row=t>>2, qtr=t&3
        {
            const int row = tid >> 2, qtr = tid & 3;
            const float* kp = kbase + ((size_t)kt * 64 + row) * HD + qtr * 32;
            float4v f[8];
#pragma unroll
            for (int i = 0; i < 8; ++i) f[i] = *(const float4v*)(kp + i * 4);
#pragma unroll
            for (int c = 0; c < 4; ++c) {
                short8v hv, lv;
#pragma unroll
                for (int j = 0; j < 8; ++j) {
                    float fv = f[2 * c + (j >> 2)][j & 3];
                    short hi = (short)f2bf(fv);
                    hv[j] = hi;
                    lv[j] = (short)f2bf(fv - bf2f(hi));
                }
                int slot = (qtr * 4 + c) ^ (row & 7);
                *(short8v*)(&Ksh[row * 128 + slot * 8]) = hv;
                *(short8v*)(&Ksl[row * 128 + slot * 8]) = lv;
            }
        }
        // ---- stage V transposed (f32 -> bf16 single round) ----
        {
            const float* vg = vbase + (size_t)kt * 64 * HD;
#pragma unroll
            for (int i = 0; i < 2; ++i) {
                int rp  = tid & 31;
                int oct = (tid >> 5) + i * 8;
                const float* p0 = vg + (size_t)(rp * 2) * HD + oct * 8;
                float4v v0a = *(const float4v*)(p0);
                float4v v0b = *(const float4v*)(p0 + 4);
                float4v v1a = *(const float4v*)(p0 + HD);
                float4v v1b = *(const float4v*)(p0 + HD + 4);
#pragma unroll
                for (int j = 0; j < 8; ++j) {
                    float f0 = (j < 4) ? v0a[j] : v0b[j - 4];
                    float f1 = (j < 4) ? v1a[j] : v1b[j - 4];
                    unsigned int pk = (unsigned short)f2bf(f0) |
                                      ((unsigned int)(unsigned short)f2bf(f1) << 16);
                    *(unsigned int*)(&Vt[oct * 8 + j][rp * 2]) = pk;
                }
            }
        }
        __syncthreads();

        // ---- QK^T 3-pass -> S^T ----
        float4v sfrag[4];
#pragma unroll
        for (int mt = 0; mt < 4; ++mt) sfrag[mt] = (float4v){0.f, 0.f, 0.f, 0.f};
#pragma unroll
        for (int mt = 0; mt < 4; ++mt) {
            int row = mt * 16 + lc;
#pragma unroll
            for (int ks = 0; ks < 4; ++ks) {
                int chunk = (ks * 4 + lg) ^ (row & 7);
                short8v kh = *(const short8v*)(&Ksh[row * 128 + chunk * 8]);
                short8v kl = *(const short8v*)(&Ksl[row * 128 + chunk * 8]);
                sfrag[mt] = __builtin_amdgcn_mfma_f32_16x16x32_bf16(kh, qh[ks], sfrag[mt], 0, 0, 0);
                sfrag[mt] = __builtin_amdgcn_mfma_f32_16x16x32_bf16(kl, qh[ks], sfrag[mt], 0, 0, 0);
                sfrag[mt] = __builtin_amdgcn_mfma_f32_16x16x32_bf16(kh, ql[ks], sfrag[mt], 0, 0, 0);
            }
        }

        // ---- causal mask + online softmax (lane owns q-col lc) ----
        float p[4][4];
        float tm = -INFINITY;
#pragma unroll
        for (int mt = 0; mt < 4; ++mt)
#pragma unroll
            for (int r = 0; r < 4; ++r) {
                int kv_abs = kt * 64 + mt * 16 + lg * 4 + r;
                float sv = sfrag[mt][r];
                if (kv_abs > q_abs) sv = -1e30f;
                p[mt][r] = sv;
                tm = fmaxf(tm, sv);
            }
        tm = fmaxf(tm, __shfl_xor(tm, 16));
        tm = fmaxf(tm, __shfl_xor(tm, 32));
        float m_new = fmaxf(m_run, tm);
        float alpha = __expf(m_run - m_new);
        float tsum = 0.f;
#pragma unroll
        for (int mt = 0; mt < 4; ++mt)
#pragma unroll
            for (int r = 0; r < 4; ++r) {
                float e = __expf(p[mt][r] - m_new);
                p[mt][r] = e;
                tsum += e;
            }
        tsum += __shfl_xor(tsum, 16);
        tsum += __shfl_xor(tsum, 32);
        l_run = l_run * alpha + tsum;
        m_run = m_new;

        // ---- P -> bf16 -> per-wave LDS ----
#pragma unroll
        for (int mt = 0; mt < 4; ++mt) {
            unsigned int w0 = f2bf(p[mt][0]) | ((unsigned int)f2bf(p[mt][1]) << 16);
            unsigned int w1 = f2bf(p[mt][2]) | ((unsigned int)f2bf(p[mt][3]) << 16);
            unsigned int* dst = (unsigned int*)(&Pl[w][lc][mt * 16 + lg * 4]);
            dst[0] = w0; dst[1] = w1;
        }

        // ---- rescale O ----
#pragma unroll
        for (int r = 0; r < 4; ++r) {
            float a_r = __shfl(alpha, lg * 4 + r);
#pragma unroll
            for (int nf = 0; nf < 8; ++nf) o[nf][r] *= a_r;
        }

        // ---- PV ----
#pragma unroll
        for (int ks2 = 0; ks2 < 2; ++ks2) {
            short8v pf = *(const short8v*)(&Pl[w][lc][ks2 * 32 + lg * 8]);
#pragma unroll
            for (int nf = 0; nf < 8; ++nf) {
                short8v vf = *(const short8v*)(&Vt[nf * 16 + lc][ks2 * 32 + lg * 8]);
                o[nf] = __builtin_amdgcn_mfma_f32_16x16x32_bf16(pf, vf, o[nf], 0, 0, 0);
            }
        }
        __syncthreads();
    }

    // ---- epilogue: ctx bf16, (b, s, h*HD+d) ----
#pragma unroll
    for (int r = 0; r < 4; ++r) {
        float inv = 1.f / __shfl(l_run, lg * 4 + r);
        int qrow = q0 + w * 16 + lg * 4 + r;
        short* dst = ctx + ((size_t)b * S + qrow) * EMB + (size_t)h * HD;
#pragma unroll
        for (int nf = 0; nf < 8; ++nf)
            dst[nf * 16 + lc] = (short)f2bf(o[nf][r] * inv);
    }
}

extern "C" void kernel_launch(void* const* d_in, const int* in_sizes, int n_in,
                              void* d_out, int out_size, void* d_ws, size_t ws_size,
                              hipStream_t stream) {
    const float* x    = (const float*)d_in[0];
    // d_in[1] = causal mask, implemented directly
    const float* cosb = (const float*)d_in[2];
    const float* sinb = (const float*)d_in[3];
    const float* Wq   = (const float*)d_in[4];
    const float* Wk   = (const float*)d_in[5];
    const float* Wv   = (const float*)d_in[6];
    const float* Wo   = (const float*)d_in[7];
    const float* qw   = (const float*)d_in[8];
    const float* kw   = (const float*)d_in[9];
    float* out = (float*)d_out;

    const int M = B * S;                           // 4096
    const size_t NQ = (size_t)B * NH * S * HD;     // 8.39M
    const size_t NK = (size_t)B * NKV * S * HD;    // 2.10M

    char* wp = (char*)d_ws;
    float* qf   = (float*)wp; wp += NQ * 4;                        // 33.55 MB
    float* kf   = (float*)wp; wp += NK * 4;                        //  8.39
    float* vf   = (float*)wp; wp += NK * 4;                        //  8.39
    short* wqh  = (short*)wp; wp += (size_t)NH * HD * EMB * 2;     //  8.39
    short* wql  = (short*)wp; wp += (size_t)NH * HD * EMB * 2;     //  8.39
    short* wkh  = (short*)wp; wp += (size_t)NKV * HD * EMB * 2;    //  2.10
    short* wkl  = (short*)wp; wp += (size_t)NKV * HD * EMB * 2;    //  2.10
    short* wvh  = (short*)wp; wp += (size_t)NKV * HD * EMB * 2;    //  2.10
    short* wvl  = (short*)wp; wp += (size_t)NKV * HD * EMB * 2;    //  2.10  (total 75.5 MB)
    // aliases (stream-ordered reuse):
    short* ctxb = wqh;   // 16.8 MB over wqh+wql — wq dead after Q GEMM
    short* wot  = wkh;   //  8.4 MB over wkh..wvl — dead after K/V GEMMs

    dim3 blk(256);

    // weight transposes + hi/lo splits
    transpose_split<<<dim3((NH * HD) / 32, EMB / 32), blk, 0, stream>>>(Wq, wqh, wql, EMB, NH * HD);
    transpose_split<<<dim3((NKV * HD) / 32, EMB / 32), blk, 0, stream>>>(Wk, wkh, wkl, EMB, NKV * HD);
    transpose_split<<<dim3((NKV * HD) / 32, EMB / 32), blk, 0, stream>>>(Wv, wvh, wvl, EMB, NKV * HD);

    // QKV projections (2-pass split-W, fp32 out, scatter (b,h,s,d))
    gemm_split<NH> <<<dim3((NH * HD) / 128, M / 128), blk, 0, stream>>>(x, wqh, wql, qf, M, NH * HD, EMB);
    gemm_split<NKV><<<dim3((NKV * HD) / 128, M / 128), blk, 0, stream>>>(x, wkh, wkl, kf, M, NKV * HD, EMB);
    gemm_split<NKV><<<dim3((NKV * HD) / 128, M / 128), blk, 0, stream>>>(x, wvh, wvl, vf, M, NKV * HD, EMB);

    // Wo transpose into the (now dead) wk/wv region
    transpose_cast<<<dim3(EMB / 32, (NH * HD) / 32), blk, 0, stream>>>(Wo, wot, NH * HD, EMB);

    // norms (+RoPE), fp32 in-place
    norm_rope<<<B * NH * S, 128, 0, stream>>>(qf, qw, cosb, sinb, 1);
    norm_rope<<<B * NKV * S, 128, 0, stream>>>(kf, kw, cosb, sinb, 1);
    norm_rope<<<B * NKV * S, 128, 0, stream>>>(vf, nullptr, nullptr, nullptr, 0);

    // attention (fp32 in, bf16 ctx out into dead wq region)
    attn_mfma<<<dim3(S / 64, NH, B), blk, 0, stream>>>(qf, kf, vf, ctxb);

    // output projection (1-pass bf16, fp32 out)
    gemm_bf16<<<dim3(EMB / 128, M / 128), blk, 0, stream>>>(ctxb, wot, out, M, EMB, EMB);
}

// Round 10
// 469.177 us; speedup vs baseline: 10.4545x; 1.6548x over previous
//
#include <hip/hip_runtime.h>
#include <hip/hip_bf16.h>
#include <math.h>
#include <stdint.h>

#define B 2
#define S 2048
#define EMB 2048
#define NH 16
#define NKV 4
#define HD 128
#define EPS 1e-6f

typedef __attribute__((ext_vector_type(8))) short short8v;   // 8 bf16 = 4 VGPR
typedef __attribute__((ext_vector_type(4))) float float4v;

static __device__ inline unsigned short f2bf(float x) {
    __hip_bfloat16 h = __float2bfloat16(x);
    return *(unsigned short*)&h;
}
static __device__ inline float bf2f(short s) {
    __hip_bfloat16 h = *(__hip_bfloat16*)&s;
    return __bfloat162float(h);
}

// async global(16B/lane) -> LDS (linear: wave-uniform base + lane*16)
static __device__ inline void gload_lds16(const void* g, void* l) {
    __builtin_amdgcn_global_load_lds(
        reinterpret_cast<const __attribute__((address_space(1))) unsigned int*>(
            reinterpret_cast<uintptr_t>(g)),
        reinterpret_cast<__attribute__((address_space(3))) unsigned int*>(
            reinterpret_cast<uintptr_t>(l)),
        16, 0, 0);
}

// ---------------- cast fp32 -> bf16 (4 elems/thread) ----------------
__global__ __launch_bounds__(256) void cast_bf16(const float* __restrict__ in,
                                                 short* __restrict__ out, int n)
{
    int i = (blockIdx.x * 256 + threadIdx.x) * 4;
    float4v v = *(const float4v*)(in + i);
    unsigned long long pk = (unsigned long long)(unsigned short)f2bf(v[0]) |
                            ((unsigned long long)(unsigned short)f2bf(v[1]) << 16) |
                            ((unsigned long long)(unsigned short)f2bf(v[2]) << 32) |
                            ((unsigned long long)(unsigned short)f2bf(v[3]) << 48);
    *(unsigned long long*)(out + i) = pk;
}

// ------------- transpose W[K][N] f32 -> Wt[N][K] bf16 (single) -------------
__global__ __launch_bounds__(256) void transpose_cast(const float* __restrict__ W,
                                                      short* __restrict__ Wt,
                                                      int K, int N)
{
    __shared__ float tile[32][33];
    const int n0 = blockIdx.x * 32, k0 = blockIdx.y * 32;
    const int tx = threadIdx.x & 31, ty = threadIdx.x >> 5;
#pragma unroll
    for (int i = 0; i < 4; ++i)
        tile[ty + i * 8][tx] = W[(size_t)(k0 + ty + i * 8) * N + n0 + tx];
    __syncthreads();
#pragma unroll
    for (int i = 0; i < 4; ++i) {
        int nr = ty + i * 8;
        Wt[(size_t)(n0 + nr) * K + k0 + tx] = (short)f2bf(tile[tx][nr]);
    }
}

// ------- transpose W[K][N] f32 -> hi/lo bf16 pair Wt_h/Wt_l [N][K] -------
__global__ __launch_bounds__(256) void transpose_split(const float* __restrict__ W,
                                                       short* __restrict__ Wth,
                                                       short* __restrict__ Wtl,
                                                       int K, int N)
{
    __shared__ float tile[32][33];
    const int n0 = blockIdx.x * 32, k0 = blockIdx.y * 32;
    const int tx = threadIdx.x & 31, ty = threadIdx.x >> 5;
#pragma unroll
    for (int i = 0; i < 4; ++i)
        tile[ty + i * 8][tx] = W[(size_t)(k0 + ty + i * 8) * N + n0 + tx];
    __syncthreads();
#pragma unroll
    for (int i = 0; i < 4; ++i) {
        int nr = ty + i * 8;
        float wv = tile[tx][nr];
        short hi = (short)f2bf(wv);
        short lo = (short)f2bf(wv - bf2f(hi));
        Wth[(size_t)(n0 + nr) * K + k0 + tx] = hi;
        Wtl[(size_t)(n0 + nr) * K + k0 + tx] = lo;
    }
}

// ------- QKV GEMM: C = A(bf16, MxK) @ (Bh+Bl)(bf16, NxK)^T, fp32 out -------
// m97 structure: 128x128 tile, BK=64, 4 waves, all staging via global_load_lds.
// MODE 0: Q scatter (16 heads -> C0). MODE 1: n<512 -> K (C0), else V (C1).
template<int MODE>
__global__ __launch_bounds__(256) void gemm_split(const short* __restrict__ A,
                                                  const short* __restrict__ Bh,
                                                  const short* __restrict__ Bl,
                                                  float* __restrict__ C0,
                                                  float* __restrict__ C1,
                                                  int M, int N, int K)
{
    __shared__ __align__(16) short As[128 * 64];    // 16 KB
    __shared__ __align__(16) short Bsh[128 * 64];   // 16 KB
    __shared__ __align__(16) short Bsl[128 * 64];   // 16 KB
    const int tid = threadIdx.x;
    const int w = tid >> 6, l = tid & 63;
    const int wr = w >> 1, wc = w & 1;
    const int lc = l & 15, lg = l >> 4;
    const int m0 = blockIdx.y * 128, n0 = blockIdx.x * 128;

    float4v acc[4][4];
#pragma unroll
    for (int mi = 0; mi < 4; ++mi)
#pragma unroll
        for (int ni = 0; ni < 4; ++ni) acc[mi][ni] = (float4v){0.f, 0.f, 0.f, 0.f};

    const int srow = tid >> 3;
    const int scol = (tid & 7) * 8;
    const short* ag  = A  + (size_t)(m0 + srow) * K + scol;
    const short* bhg = Bh + (size_t)(n0 + srow) * K + scol;
    const short* blg = Bl + (size_t)(n0 + srow) * K + scol;
    char* asl  = (char*)As  + tid * 16;
    char* bshl = (char*)Bsh + tid * 16;
    char* bsll = (char*)Bsl + tid * 16;

    for (int k0 = 0; k0 < K; k0 += 64) {
#pragma unroll
        for (int is = 0; is < 4; ++is) {
            gload_lds16(ag  + (size_t)is * 32 * K + k0, asl  + is * 4096);
            gload_lds16(bhg + (size_t)is * 32 * K + k0, bshl + is * 4096);
            gload_lds16(blg + (size_t)is * 32 * K + k0, bsll + is * 4096);
        }
        __syncthreads();

#pragma unroll
        for (int kk = 0; kk < 2; ++kk) {
            short8v af[4], bh[4], bl[4];
#pragma unroll
            for (int mi = 0; mi < 4; ++mi)
                af[mi] = *(const short8v*)(As + (wr * 64 + mi * 16 + lc) * 64 + kk * 32 + lg * 8);
#pragma unroll
            for (int ni = 0; ni < 4; ++ni) {
                int row = wc * 64 + ni * 16 + lc;
                bh[ni] = *(const short8v*)(Bsh + row * 64 + kk * 32 + lg * 8);
                bl[ni] = *(const short8v*)(Bsl + row * 64 + kk * 32 + lg * 8);
            }
#pragma unroll
            for (int mi = 0; mi < 4; ++mi)
#pragma unroll
                for (int ni = 0; ni < 4; ++ni) {
                    acc[mi][ni] = __builtin_amdgcn_mfma_f32_16x16x32_bf16(af[mi], bh[ni], acc[mi][ni], 0, 0, 0);
                    acc[mi][ni] = __builtin_amdgcn_mfma_f32_16x16x32_bf16(af[mi], bl[ni], acc[mi][ni], 0, 0, 0);
                }
        }
        __syncthreads();
    }

#pragma unroll
    for (int mi = 0; mi < 4; ++mi)
#pragma unroll
        for (int ni = 0; ni < 4; ++ni)
#pragma unroll
            for (int r = 0; r < 4; ++r) {
                int m = m0 + wr * 64 + mi * 16 + lg * 4 + r;
                int n = n0 + wc * 64 + ni * 16 + lc;
                float val = acc[mi][ni][r];
                int bb = m >> 11, ss = m & (S - 1);
                if (MODE == 0) {
                    int hh = n >> 7, dd = n & (HD - 1);
                    C0[(((size_t)bb * NH + hh) * S + ss) * HD + dd] = val;
                } else {
                    if (n < 512) {
                        int hh = n >> 7, dd = n & (HD - 1);
                        C0[(((size_t)bb * NKV + hh) * S + ss) * HD + dd] = val;
                    } else {
                        int hh = (n - 512) >> 7, dd = n & (HD - 1);
                        C1[(((size_t)bb * NKV + hh) * S + ss) * HD + dd] = val;
                    }
                }
            }
}

// ------- Wo GEMM: C = A(bf16, MxK) @ Bt(bf16, NxK)^T, fp32 out -------
__global__ __launch_bounds__(256) void gemm_bf16(const short* __restrict__ A,
                                                 const short* __restrict__ Bt,
                                                 float* __restrict__ C,
                                                 int M, int N, int K)
{
    __shared__ __align__(16) short As[128 * 64];
    __shared__ __align__(16) short Bs[128 * 64];
    const int tid = threadIdx.x;
    const int w = tid >> 6, l = tid & 63;
    const int wr = w >> 1, wc = w & 1;
    const int lc = l & 15, lg = l >> 4;
    const int m0 = blockIdx.y * 128, n0 = blockIdx.x * 128;

    float4v acc[4][4];
#pragma unroll
    for (int mi = 0; mi < 4; ++mi)
#pragma unroll
        for (int ni = 0; ni < 4; ++ni) acc[mi][ni] = (float4v){0.f, 0.f, 0.f, 0.f};

    const int srow = tid >> 3;
    const int scol = (tid & 7) * 8;
    const short* ag = A  + (size_t)(m0 + srow) * K + scol;
    const short* bg = Bt + (size_t)(n0 + srow) * K + scol;
    char* asl = (char*)As + tid * 16;
    char* bsl = (char*)Bs + tid * 16;

    for (int k0 = 0; k0 < K; k0 += 64) {
#pragma unroll
        for (int is = 0; is < 4; ++is) {
            gload_lds16(ag + (size_t)is * 32 * K + k0, asl + is * 4096);
            gload_lds16(bg + (size_t)is * 32 * K + k0, bsl + is * 4096);
        }
        __syncthreads();
#pragma unroll
        for (int kk = 0; kk < 2; ++kk) {
            short8v af[4], bf[4];
#pragma unroll
            for (int mi = 0; mi < 4; ++mi)
                af[mi] = *(const short8v*)(As + (wr * 64 + mi * 16 + lc) * 64 + kk * 32 + lg * 8);
#pragma unroll
            for (int ni = 0; ni < 4; ++ni)
                bf[ni] = *(const short8v*)(Bs + (wc * 64 + ni * 16 + lc) * 64 + kk * 32 + lg * 8);
#pragma unroll
            for (int mi = 0; mi < 4; ++mi)
#pragma unroll
                for (int ni = 0; ni < 4; ++ni)
                    acc[mi][ni] = __builtin_amdgcn_mfma_f32_16x16x32_bf16(af[mi], bf[ni], acc[mi][ni], 0, 0, 0);
        }
        __syncthreads();
    }

#pragma unroll
    for (int mi = 0; mi < 4; ++mi)
#pragma unroll
        for (int ni = 0; ni < 4; ++ni)
#pragma unroll
            for (int r = 0; r < 4; ++r) {
                int m = m0 + wr * 64 + mi * 16 + lg * 4 + r;
                int n = n0 + wc * 64 + ni * 16 + lc;
                C[(size_t)m * N + n] = acc[mi][ni][r];
            }
}

// ------- fused RMSNorm (+weight) + optional RoPE, fp32 in-place -------
__global__ __launch_bounds__(128) void norm_rope(float* __restrict__ buf,
                                                 const float* __restrict__ w,
                                                 const float* __restrict__ cosb,
                                                 const float* __restrict__ sinb,
                                                 int do_rope)
{
    const int row = blockIdx.x;
    const int s = row & (S - 1);
    const int d = threadIdx.x;
    float* p = buf + (size_t)row * HD;

    float xv = p[d];
    float ss = xv * xv;
#pragma unroll
    for (int off = 32; off > 0; off >>= 1) ss += __shfl_down(ss, off);

    __shared__ float wsum[2];
    __shared__ float xs[HD];
    const int lane = d & 63, wid = d >> 6;
    if (lane == 0) wsum[wid] = ss;
    __syncthreads();
    float ms = (wsum[0] + wsum[1]) * (1.f / HD) + EPS;
    float xn = xv * rsqrtf(ms);
    if (w) xn *= w[d];
    if (do_rope) {
        xs[d] = xn;
        __syncthreads();
        float rot = (d < 64) ? -xs[d + 64] : xs[d - 64];
        xn = xn * cosb[(size_t)s * HD + d] + rot * sinb[(size_t)s * HD + d];
    }
    p[d] = xn;
}

// ------- K pre-split: fp32 (b,kvh,s,d) -> hi/lo bf16 tiled+swizzled -------
// tile T = row>>6 (64 rows x 128 d = 16KB); within: r=row&63, chunk c(0..15)
// stored at slot c^(r&7). Matches attn's QK^T ds_read swizzle exactly.
__global__ __launch_bounds__(256) void ksplit(const float* __restrict__ kf,
                                              short* __restrict__ khs,
                                              short* __restrict__ kls)
{
    int g = blockIdx.x * 256 + threadIdx.x;       // 262144 chunks
    int row = g >> 4, c = g & 15;
    const float* src = kf + (size_t)row * HD + c * 8;
    float4v a = *(const float4v*)src;
    float4v b = *(const float4v*)(src + 4);
    int r = row & 63;
    size_t o = ((size_t)(row >> 6)) * 8192 + (size_t)r * 128 + (size_t)(c ^ (r & 7)) * 8;
    short8v hv, lv;
#pragma unroll
    for (int j = 0; j < 8; ++j) {
        float fv = (j < 4) ? a[j] : b[j - 4];
        short hi = (short)f2bf(fv);
        hv[j] = hi;
        lv[j] = (short)f2bf(fv - bf2f(hi));
    }
    *(short8v*)(khs + o) = hv;
    *(short8v*)(kls + o) = lv;
}

// ------- V pre-transpose: fp32 (b,kvh,s,d) -> bf16 Vt tiles [128 d][64 s] ----
// per tile (bk, t): chunk c (8 s-values) of row d stored at slot c^(d&7).
__global__ __launch_bounds__(256) void vtrans(const float* __restrict__ vf,
                                              short* __restrict__ vts)
{
    __shared__ float tile[64][132];
    const int bid = blockIdx.x;                   // bk*32 + t, 256 blocks
    const int tid = threadIdx.x;
    const float* src = vf + (size_t)bid * 64 * HD;
    const int row = tid >> 2, c0 = (tid & 3) * 32;
#pragma unroll
    for (int i = 0; i < 8; ++i)
        *(float4v*)(&tile[row][c0 + i * 4]) = *(const float4v*)(src + (size_t)row * HD + c0 + i * 4);
    __syncthreads();
#pragma unroll
    for (int i = 0; i < 4; ++i) {
        int g = tid + i * 256;                    // 1024 chunks
        int d = g >> 3, c = g & 7;
        short8v hv;
#pragma unroll
        for (int j = 0; j < 8; ++j) hv[j] = (short)f2bf(tile[c * 8 + j][d]);
        *(short8v*)(vts + (size_t)bid * 8192 + d * 64 + (c ^ (d & 7)) * 8) = hv;
    }
}

// ---------------- causal GQA flash attention, split-precision MFMA -----------
// grid (16, NH, B), 4 waves. Block p handles qt=p then qt=31-p (33 kt-iters,
// perfectly balanced; 512 blocks = 2/CU). K/V staged via global_load_lds from
// pre-split/pre-transposed (and pre-swizzled) buffers — zero staging VALU.
__global__ __launch_bounds__(256) void attn_mfma(const float* __restrict__ q,
                                                 const short* __restrict__ khs,
                                                 const short* __restrict__ kls,
                                                 const short* __restrict__ vts,
                                                 short* __restrict__ ctx)
{
    const int p = blockIdx.x, h = blockIdx.y, b = blockIdx.z;
    const int kvh = h >> 2;
    const int kvb = b * NKV + kvh;
    const int tid = threadIdx.x;
    const int w  = tid >> 6;
    const int l  = tid & 63;
    const int lg = l >> 4;
    const int lc = l & 15;

    __shared__ __align__(16) short Ksh[64 * 128];   // 16 KB (swizzled content)
    __shared__ __align__(16) short Ksl[64 * 128];   // 16 KB
    __shared__ __align__(16) short Vt[128 * 64];    // 16 KB (swizzled content)
    __shared__ __align__(16) short Pl[4][16][72];   // 9 KB per-wave P

    for (int ph = 0; ph < 2; ++ph) {
        const int qt = ph ? (31 - p) : p;
        const int q0 = qt * 64;
        const float* qbase = q + (((size_t)b * NH + h) * S + q0 + w * 16) * HD;

        // Q fragments hi/lo (exact split of fp32), once per phase
        short8v qh[4], ql[4];
#pragma unroll
        for (int ks = 0; ks < 4; ++ks) {
            const float* qp = qbase + lc * HD + ks * 32 + lg * 8;
            float4v a = *(const float4v*)qp;
            float4v bq = *(const float4v*)(qp + 4);
#pragma unroll
            for (int j = 0; j < 8; ++j) {
                float fv = (j < 4) ? a[j] : bq[j - 4];
                short hi = (short)f2bf(fv);
                qh[ks][j] = hi;
                ql[ks][j] = (short)f2bf(fv - bf2f(hi));
            }
        }

        float4v o[8];
#pragma unroll
        for (int nf = 0; nf < 8; ++nf) o[nf] = (float4v){0.f, 0.f, 0.f, 0.f};
        float m_run = -INFINITY, l_run = 0.f;
        const int q_abs = q0 + w * 16 + lc;

        for (int kt = 0; kt <= qt; ++kt) {
            const size_t tbase = ((size_t)(kvb * 32 + kt)) * 8192;
            const short* khg = khs + tbase;
            const short* klg = kls + tbase;
            const short* vtg = vts + tbase;
#pragma unroll
            for (int is = 0; is < 4; ++is) {
                int e = (tid + is * 256) * 8;       // element offset (16B chunk)
                gload_lds16(khg + e, (char*)Ksh + e * 2);
                gload_lds16(klg + e, (char*)Ksl + e * 2);
                gload_lds16(vtg + e, (char*)Vt  + e * 2);
            }
            __syncthreads();

            // ---- QK^T 3-pass -> S^T ----
            float4v sfrag[4];
#pragma unroll
            for (int mt = 0; mt < 4; ++mt) sfrag[mt] = (float4v){0.f, 0.f, 0.f, 0.f};
#pragma unroll
            for (int mt = 0; mt < 4; ++mt) {
                int row = mt * 16 + lc;
#pragma unroll
                for (int ks = 0; ks < 4; ++ks) {
                    int chunk = (ks * 4 + lg) ^ (row & 7);
                    short8v kh = *(const short8v*)(&Ksh[row * 128 + chunk * 8]);
                    short8v kl = *(const short8v*)(&Ksl[row * 128 + chunk * 8]);
                    sfrag[mt] = __builtin_amdgcn_mfma_f32_16x16x32_bf16(kh, qh[ks], sfrag[mt], 0, 0, 0);
                    sfrag[mt] = __builtin_amdgcn_mfma_f32_16x16x32_bf16(kl, qh[ks], sfrag[mt], 0, 0, 0);
                    sfrag[mt] = __builtin_amdgcn_mfma_f32_16x16x32_bf16(kh, ql[ks], sfrag[mt], 0, 0, 0);
                }
            }

            // ---- causal mask + online softmax (lane owns q-col lc) ----
            float pv[4][4];
            float tm = -INFINITY;
#pragma unroll
            for (int mt = 0; mt < 4; ++mt)
#pragma unroll
                for (int r = 0; r < 4; ++r) {
                    int kv_abs = kt * 64 + mt * 16 + lg * 4 + r;
                    float sv = sfrag[mt][r];
                    if (kv_abs > q_abs) sv = -1e30f;
                    pv[mt][r] = sv;
                    tm = fmaxf(tm, sv);
                }
            tm = fmaxf(tm, __shfl_xor(tm, 16));
            tm = fmaxf(tm, __shfl_xor(tm, 32));
            float m_new = fmaxf(m_run, tm);
            float alpha = __expf(m_run - m_new);
            float tsum = 0.f;
#pragma unroll
            for (int mt = 0; mt < 4; ++mt)
#pragma unroll
                for (int r = 0; r < 4; ++r) {
                    float e = __expf(pv[mt][r] - m_new);
                    pv[mt][r] = e;
                    tsum += e;
                }
            tsum += __shfl_xor(tsum, 16);
            tsum += __shfl_xor(tsum, 32);
            l_run = l_run * alpha + tsum;
            m_run = m_new;

            // ---- P -> bf16 -> per-wave LDS ----
#pragma unroll
            for (int mt = 0; mt < 4; ++mt) {
                unsigned int w0 = f2bf(pv[mt][0]) | ((unsigned int)f2bf(pv[mt][1]) << 16);
                unsigned int w1 = f2bf(pv[mt][2]) | ((unsigned int)f2bf(pv[mt][3]) << 16);
                unsigned int* dst = (unsigned int*)(&Pl[w][lc][mt * 16 + lg * 4]);
                dst[0] = w0; dst[1] = w1;
            }

            // ---- rescale O ----
#pragma unroll
            for (int r = 0; r < 4; ++r) {
                float a_r = __shfl(alpha, lg * 4 + r);
#pragma unroll
                for (int nf = 0; nf < 8; ++nf) o[nf][r] *= a_r;
            }

            // ---- PV (Vt swizzled read) ----
#pragma unroll
            for (int ks2 = 0; ks2 < 2; ++ks2) {
                short8v pf = *(const short8v*)(&Pl[w][lc][ks2 * 32 + lg * 8]);
#pragma unroll
                for (int nf = 0; nf < 8; ++nf) {
                    int row = nf * 16 + lc;
                    int chunk = (ks2 * 4 + lg) ^ (row & 7);
                    short8v vfr = *(const short8v*)(&Vt[row * 64 + chunk * 8]);
                    o[nf] = __builtin_amdgcn_mfma_f32_16x16x32_bf16(pf, vfr, o[nf], 0, 0, 0);
                }
            }
            __syncthreads();
        }

        // ---- epilogue: ctx bf16, (b, s, h*HD+d) ----
#pragma unroll
        for (int r = 0; r < 4; ++r) {
            float inv = 1.f / __shfl(l_run, lg * 4 + r);
            int qrow = q0 + w * 16 + lg * 4 + r;
            short* dst = ctx + ((size_t)b * S + qrow) * EMB + (size_t)h * HD;
#pragma unroll
            for (int nf = 0; nf < 8; ++nf)
                dst[nf * 16 + lc] = (short)f2bf(o[nf][r] * inv);
        }
    }
}

extern "C" void kernel_launch(void* const* d_in, const int* in_sizes, int n_in,
                              void* d_out, int out_size, void* d_ws, size_t ws_size,
                              hipStream_t stream) {
    const float* x    = (const float*)d_in[0];
    // d_in[1] = causal mask, implemented directly
    const float* cosb = (const float*)d_in[2];
    const float* sinb = (const float*)d_in[3];
    const float* Wq   = (const float*)d_in[4];
    const float* Wk   = (const float*)d_in[5];
    const float* Wv   = (const float*)d_in[6];
    const float* Wo   = (const float*)d_in[7];
    const float* qw   = (const float*)d_in[8];
    const float* kw   = (const float*)d_in[9];
    float* out = (float*)d_out;

    const int M = B * S;                           // 4096

    // Regions (bytes): R_xb 16.78M | R_wt 16.78M | R_qf 33.55M | R_kf 8.39M | R_vf 8.39M
    char* wp = (char*)d_ws;
    short* xb   = (short*)wp;                                  // bf16 x (dead after KV gemm)
    char*  R_wt = wp + 16777216;
    float* qf   = (float*)(wp + 2 * 16777216);
    float* kf   = (float*)(wp + 2 * 16777216 + 33554432);
    float* vf   = (float*)((char*)kf + 8388608);
    // aliases within R_wt:
    short* wqh  = (short*)R_wt;                    // 8.39M (Q weights hi)
    short* wql  = (short*)(R_wt + 8388608);        // 8.39M (Q weights lo)
    short* wkvh = (short*)R_wt;                    // 4.19M (KV weights hi; after Q gemm)
    short* wkvl = (short*)(R_wt + 4194304);        // 4.19M
    short* khs  = (short*)R_wt;                    // 4.19M (after KV gemm)
    short* kls  = (short*)(R_wt + 4194304);        // 4.19M
    short* vts  = (short*)(R_wt + 8388608);        // 4.19M
    short* wot  = xb;                              // 8.39M (after KV gemm, xb dead)
    short* ctxb = (short*)kf;                      // 16.78M over kf+vf (dead after ksplit/vtrans)

    dim3 blk(256);

    // 1. x -> bf16 (single round; identical numerics to R5's in-GEMM round)
    cast_bf16<<<(M * EMB) / 1024, blk, 0, stream>>>(x, xb, M * EMB);

    // 2-3. Q projection
    transpose_split<<<dim3((NH * HD) / 32, EMB / 32), blk, 0, stream>>>(Wq, wqh, wql, EMB, NH * HD);
    gemm_split<0><<<dim3((NH * HD) / 128, M / 128), blk, 0, stream>>>(xb, wqh, wql, qf, nullptr, M, NH * HD, EMB);

    // 4-6. fused K+V projection (N = 1024)
    transpose_split<<<dim3((NKV * HD) / 32, EMB / 32), blk, 0, stream>>>(Wk, wkvh, wkvl, EMB, NKV * HD);
    transpose_split<<<dim3((NKV * HD) / 32, EMB / 32), blk, 0, stream>>>(Wv, wkvh + (size_t)512 * EMB, wkvl + (size_t)512 * EMB, EMB, NKV * HD);
    gemm_split<1><<<dim3(1024 / 128, M / 128), blk, 0, stream>>>(xb, wkvh, wkvl, kf, vf, M, 1024, EMB);

    // 7. Wo transpose into xb region (xb dead)
    transpose_cast<<<dim3(EMB / 32, (NH * HD) / 32), blk, 0, stream>>>(Wo, wot, NH * HD, EMB);

    // 8. norms (+RoPE), fp32 in-place
    norm_rope<<<B * NH * S, 128, 0, stream>>>(qf, qw, cosb, sinb, 1);
    norm_rope<<<B * NKV * S, 128, 0, stream>>>(kf, kw, cosb, sinb, 1);
    norm_rope<<<B * NKV * S, 128, 0, stream>>>(vf, nullptr, nullptr, nullptr, 0);

    // 9-10. K hi/lo pre-split + V pre-transpose (both pre-swizzled)
    ksplit<<<(B * NKV * S * 16) / 256, blk, 0, stream>>>(kf, khs, kls);
    vtrans<<<B * NKV * (S / 64), blk, 0, stream>>>(vf, vts);

    // 11. attention (balanced qt pairing), bf16 ctx into kf/vf region
    attn_mfma<<<dim3(16, NH, B), blk, 0, stream>>>(qf, khs, kls, vts, ctxb);

    // 12. output projection
    gemm_bf16<<<dim3(EMB / 128, M / 128), blk, 0, stream>>>(ctxb, wot, out, M, EMB, EMB);
}